// Round 3
// baseline (522.038 us; speedup 1.0000x reference)
//
#include <hip/hip_runtime.h>
#include <hip/hip_bf16.h>

#define S_ 128
#define N_ 384
#define CM 256
#define CH 32
#define CZ 128

typedef __attribute__((ext_vector_type(8))) __bf16 bf16x8;
typedef __attribute__((ext_vector_type(4))) float f32x4;

union pack4 { __hip_bfloat16 h[4]; uint2 u; };

// ---- Kernel P1: wt12[64][256] bf16 = [w1|w2]^T (row ncol = output col) ----
__global__ __launch_bounds__(256) void k_w12(const float* __restrict__ w1,
                                             const float* __restrict__ w2,
                                             __hip_bfloat16* __restrict__ wt12)
{
    const int ncol = blockIdx.x, t = threadIdx.x;  // ncol 0..63, t = k
    const float* w = (ncol < CH) ? w1 : w2;
    wt12[ncol * CM + t] = __float2bfloat16(w[(size_t)t * CH + (ncol & 31)]);
}

// ---- Kernel P2: woutT[z][cd] bf16 ----------------------------------------
__global__ __launch_bounds__(256) void k_wt(const float* __restrict__ wout,
                                            __hip_bfloat16* __restrict__ woutT)
{
    const int z = blockIdx.x;
    for (int cd = threadIdx.x; cd < CH*CH; cd += 256)
        woutT[(size_t)z * (CH*CH) + cd] = __float2bfloat16(wout[(size_t)cd * CZ + z]);
}

// ---- Kernel P3: reciprocal norm ------------------------------------------
__global__ __launch_bounds__(N_) void k_rnorm(const float* __restrict__ mask,
                                              float* __restrict__ RN)
{
    const int i = blockIdx.x, j = threadIdx.x;
    float acc = 0.f;
    #pragma unroll 8
    for (int s = 0; s < S_; ++s)
        acc += mask[s*N_ + i] * mask[s*N_ + j];
    RN[i*N_ + j] = 1.0f / (acc + 1e-3f);
}

// ---- Kernel 1: LayerNorm + dual projection via MFMA ----------------------
// 384 blocks: s = bid/3, n0 = (bid%3)*128. 256 thr = 4 waves.
// Phase A: LN of 128 rows -> lnS bf16 [128][264]. Phase B: [128x256]@[256x64]
// MFMA (wt12 fragments straight from global, L1-hot). Out: At/Bt [n][c][s].
#define LNR 264
__global__ __launch_bounds__(256) void k_lnp(
    const float* __restrict__ m, const float* __restrict__ mask,
    const float* __restrict__ gamma, const float* __restrict__ beta,
    const float* __restrict__ b1, const float* __restrict__ b2,
    const __hip_bfloat16* __restrict__ wt12,
    __hip_bfloat16* __restrict__ At, __hip_bfloat16* __restrict__ Bt)
{
    __shared__ __hip_bfloat16 lnS[128 * LNR];
    __shared__ float msk[128];
    const int bid = blockIdx.x;
    const int s = bid / 3, n0 = (bid - s*3) * 128;
    const int t = threadIdx.x, wave = t >> 6, lane = t & 63;
    const int l15 = lane & 15, quad = lane >> 4;

    if (t < 128) msk[t] = mask[s*N_ + n0 + t];

    float4 g  = ((const float4*)gamma)[lane];
    float4 be = ((const float4*)beta)[lane];
    for (int i = 0; i < 32; ++i) {
        const int row = wave*32 + i;
        float4 x = ((const float4*)(m + ((size_t)(s*N_ + n0 + row)) * CM))[lane];
        float sum = x.x + x.y + x.z + x.w;
        float ssq = x.x*x.x + x.y*x.y + x.z*x.z + x.w*x.w;
        #pragma unroll
        for (int off = 32; off >= 1; off >>= 1) {
            sum += __shfl_xor(sum, off, 64);
            ssq += __shfl_xor(ssq, off, 64);
        }
        const float mean = sum * (1.0f/CM);
        const float var  = ssq * (1.0f/CM) - mean*mean;
        const float rstd = rsqrtf(var + 1e-5f);
        pack4 pk;
        pk.h[0] = __float2bfloat16((x.x - mean)*rstd*g.x + be.x);
        pk.h[1] = __float2bfloat16((x.y - mean)*rstd*g.y + be.y);
        pk.h[2] = __float2bfloat16((x.z - mean)*rstd*g.z + be.z);
        pk.h[3] = __float2bfloat16((x.w - mean)*rstd*g.w + be.w);
        *(uint2*)&lnS[row*LNR + lane*4] = pk.u;
    }
    __syncthreads();

    f32x4 acc[2][4];
    const f32x4 z4 = {0.f,0.f,0.f,0.f};
    #pragma unroll
    for (int mt = 0; mt < 2; ++mt)
        #pragma unroll
        for (int nt = 0; nt < 4; ++nt) acc[mt][nt] = z4;

    #pragma unroll
    for (int kk = 0; kk < 8; ++kk) {
        bf16x8 a0 = *(const bf16x8*)&lnS[(wave*32      + l15)*LNR + kk*32 + quad*8];
        bf16x8 a1 = *(const bf16x8*)&lnS[(wave*32 + 16 + l15)*LNR + kk*32 + quad*8];
        #pragma unroll
        for (int nt = 0; nt < 4; ++nt) {
            bf16x8 wv = *(const bf16x8*)&wt12[(size_t)(nt*16 + l15)*CM + kk*32 + quad*8];
            acc[0][nt] = __builtin_amdgcn_mfma_f32_16x16x32_bf16(a0, wv, acc[0][nt], 0,0,0);
            acc[1][nt] = __builtin_amdgcn_mfma_f32_16x16x32_bf16(a1, wv, acc[1][nt], 0,0,0);
        }
    }

    #pragma unroll
    for (int nt = 0; nt < 4; ++nt) {
        const int ncol = nt*16 + l15;
        const int sel = ncol >> 5, c = ncol & 31;
        const float bias = sel ? b2[c] : b1[c];
        __hip_bfloat16* dst = sel ? Bt : At;
        #pragma unroll
        for (int mt = 0; mt < 2; ++mt) {
            #pragma unroll
            for (int r = 0; r < 4; ++r) {
                const int mrow = wave*32 + mt*16 + quad*4 + r;
                const float v = (acc[mt][nt][r] + bias) * msk[mrow];
                dst[((size_t)(n0 + mrow)*CH + c)*S_ + s] = __float2bfloat16(v);
            }
        }
    }
}

// ---- Kernel 2: fused MFMA outer-product + w_out GEMM ---------------------
// Block = 8x4 (i,j) pairs. Stage 2: mfma(B,A) -> D regs r = consecutive d ->
// packed 8B O-writes. O bf16 [32][c*36+d], row stride 1160 (bank spread).
// Stage 3: wave w owns M-tile (w&1) x z-half (w>>1)*64 (halved LDS reads).
#define OR 1160
__global__ __launch_bounds__(256, 2) void k_opm(
    const __hip_bfloat16* __restrict__ At, const __hip_bfloat16* __restrict__ Bt,
    const float* __restrict__ RN, const __hip_bfloat16* __restrict__ woutT,
    const float* __restrict__ bout, float* __restrict__ out)
{
    __shared__ __hip_bfloat16 O[32 * OR];   // 74.2 KB, 2 blocks/CU
    const int t = threadIdx.x;
    const int wave = t >> 6, lane = t & 63;
    const int l15 = lane & 15, quad = lane >> 4;
    const int i0 = blockIdx.x * 8, j0 = blockIdx.y * 4;

    // ---- stage 2: acc[nt][mt] = D[(j,d)][(i,c)] ----
    f32x4 acc[8][4];
    const f32x4 z4 = {0.f,0.f,0.f,0.f};
    #pragma unroll
    for (int nt = 0; nt < 8; ++nt)
        #pragma unroll
        for (int mt = 0; mt < 4; ++mt) acc[nt][mt] = z4;

    const __hip_bfloat16* Ag[4];
    #pragma unroll
    for (int mt = 0; mt < 4; ++mt) {
        const int Mrow = wave*64 + mt*16 + l15;       // = i_l*32 + c
        Ag[mt] = At + ((size_t)(i0 + (Mrow >> 5)) * CH + (Mrow & 31)) * S_ + quad*8;
    }
    const __hip_bfloat16* Bg[8];
    #pragma unroll
    for (int nt = 0; nt < 8; ++nt) {
        const int Ncol = nt*16 + l15;                 // = j_l*32 + d
        Bg[nt] = Bt + ((size_t)(j0 + (Ncol >> 5)) * CH + (Ncol & 31)) * S_ + quad*8;
    }

    #pragma unroll
    for (int kk = 0; kk < 4; ++kk) {
        bf16x8 af[4], bfr[8];
        #pragma unroll
        for (int mt = 0; mt < 4; ++mt) af[mt] = *(const bf16x8*)(Ag[mt] + kk*32);
        #pragma unroll
        for (int nt = 0; nt < 8; ++nt) bfr[nt] = *(const bf16x8*)(Bg[nt] + kk*32);
        #pragma unroll
        for (int nt = 0; nt < 8; ++nt)
            #pragma unroll
            for (int mt = 0; mt < 4; ++mt)
                acc[nt][mt] = __builtin_amdgcn_mfma_f32_16x16x32_bf16(
                    bfr[nt], af[mt], acc[nt][mt], 0, 0, 0);
    }

    // ---- O writes: lane l15 -> c, (quad,r) -> d; packed b64 ----
    #pragma unroll
    for (int mt = 0; mt < 4; ++mt) {
        const int Mcol = wave*64 + mt*16 + l15;
        const int i_l = Mcol >> 5, c = Mcol & 31;
        #pragma unroll
        for (int nt = 0; nt < 8; ++nt) {
            const int j_l = nt >> 1;
            const int d0 = (nt & 1)*16 + quad*4;
            const int p = i_l*4 + j_l;
            pack4 pk;
            #pragma unroll
            for (int r = 0; r < 4; ++r) pk.h[r] = __float2bfloat16(acc[nt][mt][r]);
            *(uint2*)&O[p*OR + c*36 + d0] = pk.u;
        }
    }
    __syncthreads();

    // ---- stage 3: wave -> M-tile (wave&1), z-half (wave>>1)*64 ----
    const int mt3 = wave & 1, zb = (wave >> 1) * 64;
    f32x4 oacc[4];
    #pragma unroll
    for (int nt = 0; nt < 4; ++nt) oacc[nt] = z4;

    const __hip_bfloat16* Wg[4];
    #pragma unroll
    for (int nt = 0; nt < 4; ++nt)
        Wg[nt] = woutT + (size_t)(zb + nt*16 + l15) * (CH*CH) + quad*8;

    const __hip_bfloat16* Orow = O + (mt3*16 + l15) * OR + quad*8;
    #pragma unroll 4
    for (int kk = 0; kk < 32; ++kk) {
        bf16x8 a = *(const bf16x8*)(Orow + kk*36);
        #pragma unroll
        for (int nt = 0; nt < 4; ++nt) {
            bf16x8 b = *(const bf16x8*)(Wg[nt] + kk*32);
            oacc[nt] = __builtin_amdgcn_mfma_f32_16x16x32_bf16(a, b, oacc[nt], 0,0,0);
        }
    }

    // ---- epilogue ----
    #pragma unroll
    for (int nt = 0; nt < 4; ++nt) {
        const int zc = zb + nt*16 + l15;
        const float bz = bout[zc];
        #pragma unroll
        for (int r = 0; r < 4; ++r) {
            const int p = mt3*16 + quad*4 + r;
            const int i = i0 + (p >> 2), j = j0 + (p & 3);
            const float rn = RN[i*N_ + j];
            out[((size_t)(i*N_ + j))*CZ + zc] = (oacc[nt][r] + bz) * rn;
        }
    }
}

extern "C" void kernel_launch(void* const* d_in, const int* in_sizes, int n_in,
                              void* d_out, int out_size, void* d_ws, size_t ws_size,
                              hipStream_t stream)
{
    const float* m    = (const float*)d_in[0];
    const float* mask = (const float*)d_in[1];
    const float* gam  = (const float*)d_in[2];
    const float* bet  = (const float*)d_in[3];
    const float* w1   = (const float*)d_in[4];
    const float* b1   = (const float*)d_in[5];
    const float* w2   = (const float*)d_in[6];
    const float* b2   = (const float*)d_in[7];
    const float* wout = (const float*)d_in[8];
    const float* bout = (const float*)d_in[9];
    float* out = (float*)d_out;

    __hip_bfloat16* At    = (__hip_bfloat16*)d_ws;                 // [N][CH][S]
    __hip_bfloat16* Bt    = At + (size_t)N_ * CH * S_;             // [N][CH][S]
    __hip_bfloat16* woutT = Bt + (size_t)N_ * CH * S_;             // [CZ][1024]
    __hip_bfloat16* wt12  = woutT + (size_t)CZ * CH * CH;          // [64][256]
    float*          RN    = (float*)(wt12 + (size_t)64 * CM);      // [N][N]

    k_w12<<<64, 256, 0, stream>>>(w1, w2, wt12);
    k_wt<<<CZ, 256, 0, stream>>>(wout, woutT);
    k_rnorm<<<N_, N_, 0, stream>>>(mask, RN);
    k_lnp<<<384, 256, 0, stream>>>(m, mask, gam, bet, b1, b2, wt12, At, Bt);
    dim3 grid(N_ / 8, N_ / 4);
    k_opm<<<grid, 256, 0, stream>>>(At, Bt, RN, woutT, bout, out);
}

// Round 4
// 329.130 us; speedup vs baseline: 1.5861x; 1.5861x over previous
//
#include <hip/hip_runtime.h>
#include <hip/hip_bf16.h>

#define S_ 128
#define N_ 384
#define CM 256
#define CH 32
#define CZ 128

typedef __attribute__((ext_vector_type(8))) __bf16 bf16x8;
typedef __attribute__((ext_vector_type(4))) float f32x4;

union pack4 { __hip_bfloat16 h[4]; uint2 u; };

// ---- Kernel P1: wt12[64][256] bf16 = [w1|w2]^T ---------------------------
__global__ __launch_bounds__(256) void k_w12(const float* __restrict__ w1,
                                             const float* __restrict__ w2,
                                             __hip_bfloat16* __restrict__ wt12)
{
    const int ncol = blockIdx.x, t = threadIdx.x;
    const float* w = (ncol < CH) ? w1 : w2;
    wt12[ncol * CM + t] = __float2bfloat16(w[(size_t)t * CH + (ncol & 31)]);
}

// ---- Kernel P2: woutT[z][cd] bf16 ----------------------------------------
__global__ __launch_bounds__(256) void k_wt(const float* __restrict__ wout,
                                            __hip_bfloat16* __restrict__ woutT)
{
    const int z = blockIdx.x;
    for (int cd = threadIdx.x; cd < CH*CH; cd += 256)
        woutT[(size_t)z * (CH*CH) + cd] = __float2bfloat16(wout[(size_t)cd * CZ + z]);
}

// ---- Kernel P3: reciprocal norm ------------------------------------------
__global__ __launch_bounds__(N_) void k_rnorm(const float* __restrict__ mask,
                                              float* __restrict__ RN)
{
    const int i = blockIdx.x, j = threadIdx.x;
    float acc = 0.f;
    #pragma unroll 8
    for (int s = 0; s < S_; ++s)
        acc += mask[s*N_ + i] * mask[s*N_ + j];
    RN[i*N_ + j] = 1.0f / (acc + 1e-3f);
}

// ---- Kernel 1: LayerNorm + dual projection via MFMA ----------------------
// Block = 16 n x 8 s (128 LN rows, row = n*8+s). Grid 24 x 16. 256 thr.
// D-regs r = 4 consecutive s for fixed (n,c) -> packed uint2 stores into
// At/Bt [n][c][s] (kills the R3 2-B scatter).
#define LNR 264
__global__ __launch_bounds__(256) void k_lnp(
    const float* __restrict__ m, const float* __restrict__ mask,
    const float* __restrict__ gamma, const float* __restrict__ beta,
    const float* __restrict__ b1, const float* __restrict__ b2,
    const __hip_bfloat16* __restrict__ wt12,
    __hip_bfloat16* __restrict__ At, __hip_bfloat16* __restrict__ Bt)
{
    __shared__ __hip_bfloat16 lnS[128 * LNR];
    __shared__ float msk[128];
    const int n0 = blockIdx.x * 16, s0 = blockIdx.y * 8;
    const int t = threadIdx.x, wave = t >> 6, lane = t & 63;
    const int l15 = lane & 15, quad = lane >> 4;

    if (t < 128) msk[t] = mask[(s0 + (t & 7))*N_ + n0 + (t >> 3)];

    float4 g  = ((const float4*)gamma)[lane];
    float4 be = ((const float4*)beta)[lane];
    for (int i = 0; i < 32; ++i) {
        const int row = wave*32 + i;
        const int n = row >> 3, s = row & 7;
        float4 x = ((const float4*)(m + ((size_t)((s0+s)*N_ + n0 + n)) * CM))[lane];
        float sum = x.x + x.y + x.z + x.w;
        float ssq = x.x*x.x + x.y*x.y + x.z*x.z + x.w*x.w;
        #pragma unroll
        for (int off = 32; off >= 1; off >>= 1) {
            sum += __shfl_xor(sum, off, 64);
            ssq += __shfl_xor(ssq, off, 64);
        }
        const float mean = sum * (1.0f/CM);
        const float var  = ssq * (1.0f/CM) - mean*mean;
        const float rstd = rsqrtf(var + 1e-5f);
        pack4 pk;
        pk.h[0] = __float2bfloat16((x.x - mean)*rstd*g.x + be.x);
        pk.h[1] = __float2bfloat16((x.y - mean)*rstd*g.y + be.y);
        pk.h[2] = __float2bfloat16((x.z - mean)*rstd*g.z + be.z);
        pk.h[3] = __float2bfloat16((x.w - mean)*rstd*g.w + be.w);
        *(uint2*)&lnS[row*LNR + lane*4] = pk.u;
    }
    __syncthreads();

    f32x4 acc[2][4];
    const f32x4 z4 = {0.f,0.f,0.f,0.f};
    #pragma unroll
    for (int mt = 0; mt < 2; ++mt)
        #pragma unroll
        for (int nt = 0; nt < 4; ++nt) acc[mt][nt] = z4;

    #pragma unroll
    for (int kk = 0; kk < 8; ++kk) {
        bf16x8 a0 = *(const bf16x8*)&lnS[(wave*32      + l15)*LNR + kk*32 + quad*8];
        bf16x8 a1 = *(const bf16x8*)&lnS[(wave*32 + 16 + l15)*LNR + kk*32 + quad*8];
        #pragma unroll
        for (int nt = 0; nt < 4; ++nt) {
            bf16x8 wv = *(const bf16x8*)&wt12[(size_t)(nt*16 + l15)*CM + kk*32 + quad*8];
            acc[0][nt] = __builtin_amdgcn_mfma_f32_16x16x32_bf16(a0, wv, acc[0][nt], 0,0,0);
            acc[1][nt] = __builtin_amdgcn_mfma_f32_16x16x32_bf16(a1, wv, acc[1][nt], 0,0,0);
        }
    }

    // store: row = wave*32 + mt*16 + quad*4 + r; n = row>>3, s = s0 + (row&7)
    #pragma unroll
    for (int nt = 0; nt < 4; ++nt) {
        const int ncol = nt*16 + l15;
        const int sel = ncol >> 5, c = ncol & 31;
        const float bias = sel ? b2[c] : b1[c];
        __hip_bfloat16* dst = sel ? Bt : At;
        #pragma unroll
        for (int mt = 0; mt < 2; ++mt) {
            const int rowb = wave*32 + mt*16 + quad*4;
            const int n_loc = rowb >> 3, s_loc = rowb & 7;   // r spans s_loc..s_loc+3
            pack4 pk;
            #pragma unroll
            for (int r = 0; r < 4; ++r)
                pk.h[r] = __float2bfloat16((acc[mt][nt][r] + bias) * msk[rowb + r]);
            *(uint2*)&dst[((size_t)(n0 + n_loc)*CH + c)*S_ + s0 + s_loc] = pk.u;
        }
    }
}

// ---- Kernel 2: fused MFMA outer-product + w_out GEMM ---------------------
// Block = 8x8 (i,j) pairs (64), 512 thr = 8 waves, grid 48x48.
// Stage 2: M=256 (i*32+c), N=256 (j*32+d), K=128. Wave: M-half x N-quarter,
//   8x4 tiles, mfma(B,A) -> packed uint2 O-writes (R3 layout, OR c-stride 36).
// Stage 3: wave owns exclusive 16-z slice; ALL 32 woutT k-fragments preloaded
//   into 128 VGPRs (one L2 burst, 256 KB/block) -> kk-loop is pure LDS+MFMA.
#define OR 1160
__global__ __launch_bounds__(512) void k_opm(
    const __hip_bfloat16* __restrict__ At, const __hip_bfloat16* __restrict__ Bt,
    const float* __restrict__ RN, const __hip_bfloat16* __restrict__ woutT,
    const float* __restrict__ bout, float* __restrict__ out)
{
    __shared__ __hip_bfloat16 O[64 * OR];   // 145 KB
    const int t = threadIdx.x;
    const int wave = t >> 6, lane = t & 63;
    const int l15 = lane & 15, quad = lane >> 4;
    const int i0 = blockIdx.x * 8, j0 = blockIdx.y * 8;
    const int mhalf = wave & 1, nquad = wave >> 1;

    // ---- stage 2: acc[nt][mt] = D[(j,d)][(i,c)] ----
    f32x4 acc[4][8];
    const f32x4 z4 = {0.f,0.f,0.f,0.f};
    #pragma unroll
    for (int nt = 0; nt < 4; ++nt)
        #pragma unroll
        for (int mt = 0; mt < 8; ++mt) acc[nt][mt] = z4;

    const __hip_bfloat16* Ag[8];
    #pragma unroll
    for (int mt = 0; mt < 8; ++mt) {
        const int Mrow = mhalf*128 + mt*16 + l15;     // = i_l*32 + c
        Ag[mt] = At + ((size_t)(i0 + (Mrow >> 5)) * CH + (Mrow & 31)) * S_ + quad*8;
    }
    const __hip_bfloat16* Bg[4];
    #pragma unroll
    for (int nt = 0; nt < 4; ++nt) {
        const int Ncol = nquad*64 + nt*16 + l15;      // = j_l*32 + d
        Bg[nt] = Bt + ((size_t)(j0 + (Ncol >> 5)) * CH + (Ncol & 31)) * S_ + quad*8;
    }

    #pragma unroll
    for (int kk = 0; kk < 4; ++kk) {
        bf16x8 af[8], bfr[4];
        #pragma unroll
        for (int mt = 0; mt < 8; ++mt) af[mt] = *(const bf16x8*)(Ag[mt] + kk*32);
        #pragma unroll
        for (int nt = 0; nt < 4; ++nt) bfr[nt] = *(const bf16x8*)(Bg[nt] + kk*32);
        #pragma unroll
        for (int nt = 0; nt < 4; ++nt)
            #pragma unroll
            for (int mt = 0; mt < 8; ++mt)
                acc[nt][mt] = __builtin_amdgcn_mfma_f32_16x16x32_bf16(
                    bfr[nt], af[mt], acc[nt][mt], 0, 0, 0);
    }

    // ---- O writes: col(l15) -> (i,c); row(quad,r) -> (j,d), r = consec d ----
    #pragma unroll
    for (int mt = 0; mt < 8; ++mt) {
        const int Mcol = mhalf*128 + mt*16 + l15;
        const int i_l = Mcol >> 5, c = Mcol & 31;
        #pragma unroll
        for (int nt = 0; nt < 4; ++nt) {
            const int Nrow = nquad*64 + nt*16 + quad*4;
            const int j_l = Nrow >> 5, d0 = Nrow & 31;
            const int p = i_l*8 + j_l;
            pack4 pk;
            #pragma unroll
            for (int r = 0; r < 4; ++r) pk.h[r] = __float2bfloat16(acc[nt][mt][r]);
            *(uint2*)&O[p*OR + c*36 + d0] = pk.u;
        }
    }
    __syncthreads();

    // ---- stage 3: preload woutT fragments for this wave's 16-z slice ----
    const int zb = wave * 16;
    bf16x8 wf[32];
    #pragma unroll
    for (int kk = 0; kk < 32; ++kk)
        wf[kk] = *(const bf16x8*)&woutT[(size_t)(zb + l15) * (CH*CH) + kk*32 + quad*8];

    f32x4 oacc[4];
    #pragma unroll
    for (int mt = 0; mt < 4; ++mt) oacc[mt] = z4;

    #pragma unroll
    for (int kk = 0; kk < 32; ++kk) {
        #pragma unroll
        for (int mt = 0; mt < 4; ++mt) {
            bf16x8 a = *(const bf16x8*)&O[(mt*16 + l15)*OR + kk*36 + quad*8];
            oacc[mt] = __builtin_amdgcn_mfma_f32_16x16x32_bf16(a, wf[kk], oacc[mt], 0,0,0);
        }
    }

    // ---- epilogue: col(l15) -> z, row(quad,r) -> p ----
    const int zc = zb + l15;
    const float bz = bout[zc];
    #pragma unroll
    for (int mt = 0; mt < 4; ++mt) {
        #pragma unroll
        for (int r = 0; r < 4; ++r) {
            const int p = mt*16 + quad*4 + r;
            const int i = i0 + (p >> 3), j = j0 + (p & 7);
            const float rn = RN[i*N_ + j];
            out[((size_t)(i*N_ + j))*CZ + zc] = (oacc[mt][r] + bz) * rn;
        }
    }
}

extern "C" void kernel_launch(void* const* d_in, const int* in_sizes, int n_in,
                              void* d_out, int out_size, void* d_ws, size_t ws_size,
                              hipStream_t stream)
{
    const float* m    = (const float*)d_in[0];
    const float* mask = (const float*)d_in[1];
    const float* gam  = (const float*)d_in[2];
    const float* bet  = (const float*)d_in[3];
    const float* w1   = (const float*)d_in[4];
    const float* b1   = (const float*)d_in[5];
    const float* w2   = (const float*)d_in[6];
    const float* b2   = (const float*)d_in[7];
    const float* wout = (const float*)d_in[8];
    const float* bout = (const float*)d_in[9];
    float* out = (float*)d_out;

    __hip_bfloat16* At    = (__hip_bfloat16*)d_ws;                 // [N][CH][S]
    __hip_bfloat16* Bt    = At + (size_t)N_ * CH * S_;             // [N][CH][S]
    __hip_bfloat16* woutT = Bt + (size_t)N_ * CH * S_;             // [CZ][1024]
    __hip_bfloat16* wt12  = woutT + (size_t)CZ * CH * CH;          // [64][256]
    float*          RN    = (float*)(wt12 + (size_t)64 * CM);      // [N][N]

    k_w12<<<64, 256, 0, stream>>>(w1, w2, wt12);
    k_wt<<<CZ, 256, 0, stream>>>(wout, woutT);
    k_rnorm<<<N_, N_, 0, stream>>>(mask, RN);
    dim3 gl(24, 16);
    k_lnp<<<gl, 256, 0, stream>>>(m, mask, gam, bet, b1, b2, wt12, At, Bt);
    dim3 grid(N_ / 8, N_ / 8);
    k_opm<<<grid, 512, 0, stream>>>(At, Bt, RN, woutT, bout, out);
}